// Round 6
// baseline (81.985 us; speedup 1.0000x reference)
//
#include <hip/hip_runtime.h>

#define TPB 256
#define NBLK 2048
#define NW (NBLK * TPB / 64)   // 8192 waves

template <int CTRL>
__device__ __forceinline__ float dpp_add(float v) {
    int x = __builtin_amdgcn_update_dpp(0, __float_as_int(v), CTRL, 0xf, 0xf, true);
    return v + __int_as_float(x);
}

__device__ __forceinline__ float reduce16(float s) {
    s = dpp_add<0xB1>(s);    // quad_perm xor1
    s = dpp_add<0x4E>(s);    // quad_perm xor2
    s = dpp_add<0x124>(s);   // row_ror:4
    s = dpp_add<0x128>(s);   // row_ror:8
    return s;
}

// value mask uses the ORIGINAL chunk position b4; aliased lanes (which loaded a
// redirected chunk) have b4+3 < idx so every element masks to zero.
__device__ __forceinline__ float masked_val(float4 v, int idx, int b4, int c) {
    float ms = (b4     >= idx ? v.x : 0.f)
             + (b4 + 1 >= idx ? v.y : 0.f)
             + (b4 + 2 >= idx ? v.z : 0.f)
             + (b4 + 3 >= idx ? v.w : 0.f);
    return idx ? ms : ((c == 0) ? v.x : 0.f);
}

// redirect unneeded lanes to the first needed chunk: same lines touched, no exec mask
__device__ __forceinline__ int eff_off(int idx, int c) {
    int c0 = idx >> 2;
    int ce = c < c0 ? c0 : c;
    ce = idx ? ce : 0;
    return ce << 2;
}

__device__ __forceinline__ float nll_term(float s, int i, const float* __restrict__ w) {
    return -__logf(fminf(fmaxf(s, 1e-15f), 1.0f)) * w[i];
}

__global__ __launch_bounds__(TPB, 8) void CLL_main(
    const float* __restrict__ y_pred,
    const int*   __restrict__ y_true,
    const float* __restrict__ w,
    float*       __restrict__ partial,
    const int B)
{
    const int lane = threadIdx.x & 63;
    const int wv   = threadIdx.x >> 6;   // wave within block (0..3)
    const int c    = lane & 15;          // chunk within row (4 floats)
    const int sub  = lane >> 4;          // row within quad
    const int b4   = c << 2;
    const int wid  = (blockIdx.x * TPB + threadIdx.x) >> 6;
    const int nw   = NW;
    const int nquads = (B + 3) >> 2;

    float local = 0.0f;
    int qi = wid;

    if (qi + 3 * nw < nquads) {
        int i0 = y_true[(qi         ) * 4 + sub];
        int i1 = y_true[(qi +     nw) * 4 + sub];
        int i2 = y_true[(qi + 2 * nw) * 4 + sub];
        int i3 = y_true[(qi + 3 * nw) * 4 + sub];
        for (;;) {
            const int r0 = (qi         ) * 4 + sub;
            const int r1 = (qi +     nw) * 4 + sub;
            const int r2 = (qi + 2 * nw) * 4 + sub;
            const int r3 = (qi + 3 * nw) * 4 + sub;

            // unconditional redirected loads — pure VMEM burst, no exec writes
            const float4 v0 = *(const float4*)(y_pred + r0 * 64 + eff_off(i0, c));
            const float4 v1 = *(const float4*)(y_pred + r1 * 64 + eff_off(i1, c));
            const float4 v2 = *(const float4*)(y_pred + r2 * 64 + eff_off(i2, c));
            const float4 v3 = *(const float4*)(y_pred + r3 * 64 + eff_off(i3, c));

            // prefetch next iteration's idx under the loads above
            const int qn = qi + 4 * nw;
            const bool more = (qn + 3 * nw < nquads);   // wave-uniform
            int n0 = 0, n1 = 0, n2 = 0, n3 = 0;
            if (more) {
                n0 = y_true[(qn         ) * 4 + sub];
                n1 = y_true[(qn +     nw) * 4 + sub];
                n2 = y_true[(qn + 2 * nw) * 4 + sub];
                n3 = y_true[(qn + 3 * nw) * 4 + sub];
            }

            const float s0 = reduce16(masked_val(v0, i0, b4, c));
            const float s1 = reduce16(masked_val(v1, i1, b4, c));
            const float s2 = reduce16(masked_val(v2, i2, b4, c));
            const float s3 = reduce16(masked_val(v3, i3, b4, c));

            if (c == 0) {
                local += nll_term(s0, i0, w);
                local += nll_term(s1, i1, w);
                local += nll_term(s2, i2, w);
                local += nll_term(s3, i3, w);
            }

            qi = qn;
            if (!more) break;
            i0 = n0; i1 = n1; i2 = n2; i3 = n3;
        }
    }

    // tail: one quad at a time with validity (not taken for B = 2^21)
    for (; qi < nquads; qi += nw) {
        const int r = qi * 4 + sub;
        const bool valid = r < B;
        int idx = 0;
        if (valid) idx = y_true[r];
        float4 v = {0,0,0,0};
        if (valid) v = *(const float4*)(y_pred + r * 64 + eff_off(idx, c));
        const float s = reduce16(masked_val(v, idx, b4, c));
        if (c == 0 && valid) local += nll_term(s, idx, w);
    }

    // wave sum, then block sum via LDS -> one partial per block
    #pragma unroll
    for (int off = 32; off; off >>= 1) local += __shfl_xor(local, off, 64);
    __shared__ float bred[TPB / 64];
    if (lane == 0) bred[wv] = local;
    __syncthreads();
    if (threadIdx.x == 0)
        partial[blockIdx.x] = bred[0] + bred[1] + bred[2] + bred[3];
}

__global__ __launch_bounds__(1024) void CLL_final(
    const float* __restrict__ partial, float* __restrict__ out, const int B)
{
    __shared__ double red[16];
    double s = 0.0;
    for (int i = threadIdx.x; i < NBLK; i += 1024) s += (double)partial[i];
    #pragma unroll
    for (int off = 32; off; off >>= 1) s += __shfl_xor(s, off, 64);
    if ((threadIdx.x & 63) == 0) red[threadIdx.x >> 6] = s;
    __syncthreads();
    if (threadIdx.x == 0) {
        double t = 0.0;
        #pragma unroll
        for (int i = 0; i < 16; ++i) t += red[i];
        out[0] = (float)(t / (double)B);
    }
}

extern "C" void kernel_launch(void* const* d_in, const int* in_sizes, int n_in,
                              void* d_out, int out_size, void* d_ws, size_t ws_size,
                              hipStream_t stream) {
    const float* y_pred = (const float*)d_in[0];
    const int*   y_true = (const int*)d_in[1];
    const float* w      = (const float*)d_in[2];
    float* out  = (float*)d_out;
    float* part = (float*)d_ws;

    const int B = in_sizes[1];   // rows (y_true has B elements)

    CLL_main<<<NBLK, TPB, 0, stream>>>(y_pred, y_true, w, part, B);
    CLL_final<<<1, 1024, 0, stream>>>(part, out, B);
}